// Round 13
// baseline (346.626 us; speedup 1.0000x reference)
//
#include <hip/hip_runtime.h>
#include <math.h>

#define BLOCK 256
#define NB    16
#define NN_   4096
#define MM_   4096
#define NITER 5
#define P     4
#define SCH   4
#define KCH   32
#define TCH   128
#define KCHF  16
#define TCHF  256
#define SCH2  4
#define P2    4

// ws layout (float offsets)
#define OFF_STATS 0
#define OFF_T     64
#define OFF_CH    320
#define OFF_PART  336
#define OFF_ND    2048
#define OFF_FA    67584
#define OFF_FB    133120
#define CLR_BASE  2048
#define CLR_CNT   196608

typedef __attribute__((ext_vector_type(2))) float f32x2;
typedef __attribute__((ext_vector_type(4))) float f32x4;

__device__ __forceinline__ f32x2 pk_fma(f32x2 a, f32x2 b, f32x2 c) {
  f32x2 d;
  asm("v_pk_fma_f32 %0, %1, %2, %3" : "=v"(d) : "v"(a), "v"(b), "v"(c));
  return d;
}

__device__ __forceinline__ void atomic_min_f(float* p, float v) {
  atomicMin((unsigned int*)p, __float_as_uint(v));  // valid for v >= 0
}

// ------------------------------------------------- init + clear minbufs ---
__global__ __launch_bounds__(BLOCK) void icp_init(const float* __restrict__ src,
                                                  float* __restrict__ ws) {
  int b = blockIdx.x, tid = threadIdx.x;
  for (int i = b*BLOCK + tid; i < CLR_CNT; i += NB*BLOCK)
    ws[CLR_BASE + i] = INFINITY;
  const float* sb = src + (size_t)b * NN_ * 3;
  float sx = 0.f, sy = 0.f, sz = 0.f, ss = 0.f;
  for (int n = tid; n < NN_; n += BLOCK) {
    float x = sb[3*n], y = sb[3*n+1], z = sb[3*n+2];
    sx += x; sy += y; sz += z;
    ss += fmaf(x, x, fmaf(y, y, z*z));
  }
  __shared__ float red[16];
  for (int m = 32; m; m >>= 1) {
    sx += __shfl_xor(sx, m); sy += __shfl_xor(sy, m);
    sz += __shfl_xor(sz, m); ss += __shfl_xor(ss, m);
  }
  int wave = tid >> 6;
  if ((tid & 63) == 0) {
    red[wave*4+0] = sx; red[wave*4+1] = sy; red[wave*4+2] = sz; red[wave*4+3] = ss;
  }
  __syncthreads();
  if (tid == 0) {
    for (int w = 1; w < 4; ++w) {
      sx += red[w*4+0]; sy += red[w*4+1]; sz += red[w*4+2]; ss += red[w*4+3];
    }
    float* st = ws + OFF_STATS + b*4;
    st[0] = sx; st[1] = sy; st[2] = sz; st[3] = ss;
    float* T = ws + OFF_T + b*16;
    T[0]=1.f; T[1]=0.f; T[2]=0.f;
    T[3]=0.f; T[4]=1.f; T[5]=0.f;
    T[6]=0.f; T[7]=0.f; T[8]=1.f;
    T[9]=0.f; T[10]=0.f; T[11]=0.f; T[12]=1.f;
  }
}

// ---------------------------------------------------------- NN pass 1 -----
__global__ __launch_bounds__(BLOCK, 8) void icp_nn1(const float* __restrict__ src,
                                                    const float* __restrict__ tgt,
                                                    float* __restrict__ ws) {
  __shared__ __align__(16) float tx_[TCH], ty_[TCH], tz_[TCH], tw_[TCH];
  int b = blockIdx.z, kc = blockIdx.y, tid = threadIdx.x;
  int n0 = blockIdx.x * (BLOCK * P) + tid;
  const float* T = ws + OFF_T + b*16;
  float sc = T[12];
  f32x2 nxp[P], nyp[P], nzp[P], p2p[P];
#pragma unroll
  for (int k = 0; k < P; ++k) {
    const float* sp = src + ((size_t)b * NN_ + n0 + k*BLOCK) * 3;
    float sx = sp[0], sy = sp[1], sz = sp[2];
    float px = fmaf(sc, fmaf(T[0], sx, fmaf(T[1], sy, T[2]*sz)), T[9]);
    float py = fmaf(sc, fmaf(T[3], sx, fmaf(T[4], sy, T[5]*sz)), T[10]);
    float pz = fmaf(sc, fmaf(T[6], sx, fmaf(T[7], sy, T[8]*sz)), T[11]);
    nxp[k].x = nxp[k].y = -2.f*px;
    nyp[k].x = nyp[k].y = -2.f*py;
    nzp[k].x = nzp[k].y = -2.f*pz;
    float p2 = fmaf(px, px, fmaf(py, py, pz*pz));
    p2p[k].x = p2p[k].y = p2;
  }
  if (tid < TCH) {
    int j = tid;
    const float* tp = tgt + ((size_t)b * MM_ + kc * TCH + j) * 3;
    float tx = tp[0], ty = tp[1], tz = tp[2];
    tx_[j] = tx; ty_[j] = ty; tz_[j] = tz;
    tw_[j] = fmaf(tx, tx, fmaf(ty, ty, tz*tz));
  }
  __syncthreads();

  int jbase = kc * TCH;
  float best[P];
#pragma unroll
  for (int k = 0; k < P; ++k) best[k] = INFINITY;
#pragma unroll 2
  for (int j = 0; j < TCH; j += 4) {
    f32x4 X = *(const f32x4*)&tx_[j];
    f32x4 Y = *(const f32x4*)&ty_[j];
    f32x4 Z = *(const f32x4*)&tz_[j];
    f32x4 W = *(const f32x4*)&tw_[j];
    f32x2 X0 = {X.x, X.y}, X1 = {X.z, X.w};
    f32x2 Y0 = {Y.x, Y.y}, Y1 = {Y.z, Y.w};
    f32x2 Z0 = {Z.x, Z.y}, Z1 = {Z.z, Z.w};
    f32x2 W0 = {W.x, W.y}, W1 = {W.z, W.w};
    unsigned i0 = (unsigned)(jbase + j), i1 = i0+1, i2 = i0+2, i3 = i0+3;
#pragma unroll
    for (int k = 0; k < P; ++k) {
      f32x2 v0 = pk_fma(nxp[k], X0, pk_fma(nyp[k], Y0, pk_fma(nzp[k], Z0, W0 + p2p[k])));
      f32x2 v1 = pk_fma(nxp[k], X1, pk_fma(nyp[k], Y1, pk_fma(nzp[k], Z1, W1 + p2p[k])));
      float q0 = __uint_as_float((__float_as_uint(v0.x) & 0xFFFFF000u) | i0);
      float q1 = __uint_as_float((__float_as_uint(v0.y) & 0xFFFFF000u) | i1);
      float q2 = __uint_as_float((__float_as_uint(v1.x) & 0xFFFFF000u) | i2);
      float q3 = __uint_as_float((__float_as_uint(v1.y) & 0xFFFFF000u) | i3);
      best[k] = fminf(fminf(fminf(q0, q1), fminf(q2, q3)), best[k]);
    }
  }
#pragma unroll
  for (int k = 0; k < P; ++k)
    atomic_min_f(ws + OFF_ND + (size_t)b*NN_ + n0 + k*BLOCK, best[k]);
}

// ----------------------------------------- NN pass 2: gather + 12-sums ----
__global__ __launch_bounds__(BLOCK) void icp_nn2(const float* __restrict__ src,
                                                 const float* __restrict__ tgt,
                                                 float* __restrict__ ws) {
  __shared__ float red[4*12];
  int b = blockIdx.y, c4 = blockIdx.x, tid = threadIdx.x;
  float acc[12];
#pragma unroll
  for (int c = 0; c < 12; ++c) acc[c] = 0.f;
  for (int k = 0; k < P2; ++k) {
    int n = c4 * (BLOCK*P2) + tid + k*BLOCK;
    size_t slot = OFF_ND + (size_t)b*NN_ + n;
    float bd = ws[slot];
    ws[slot] = INFINITY;  // reset for next iteration
    int bi = (int)(__float_as_uint(bd) & 4095u);
    const float* tp = tgt + ((size_t)b * MM_ + bi) * 3;
    const float* sp = src + ((size_t)b * NN_ + n) * 3;
    float tx = tp[0], ty = tp[1], tz = tp[2];
    float sx = sp[0], sy = sp[1], sz = sp[2];
    acc[0] += tx; acc[1] += ty; acc[2] += tz;
    acc[3] += sx*tx; acc[4] += sx*ty; acc[5] += sx*tz;
    acc[6] += sy*tx; acc[7] += sy*ty; acc[8] += sy*tz;
    acc[9] += sz*tx; acc[10] += sz*ty; acc[11] += sz*tz;
  }
#pragma unroll
  for (int c = 0; c < 12; ++c)
    for (int m = 32; m; m >>= 1) acc[c] += __shfl_xor(acc[c], m);
  int wave = tid >> 6;
  if ((tid & 63) == 0) {
#pragma unroll
    for (int c = 0; c < 12; ++c) red[wave*12 + c] = acc[c];
  }
  __syncthreads();
  if (tid < 12) {
    float s = red[tid] + red[12+tid] + red[24+tid] + red[36+tid];
    ws[OFF_PART + (b*SCH2 + c4)*12 + tid] = s;
  }
}

// --------------------------------------------------- Umeyama (fp32) -------
__global__ __launch_bounds__(64) void icp_umeyama(float* __restrict__ ws) {
  int b = blockIdx.x, tid = threadIdx.x;
  __shared__ float sums[12];
  if (tid < 12) {
    double s = 0.0;
    for (int j = 0; j < SCH2; ++j)
      s += (double)ws[OFF_PART + (b*SCH2 + j)*12 + tid];
    sums[tid] = (float)s;
  }
  __syncthreads();
  if (tid != 0) return;

  const float* st = ws + OFF_STATS + b*4;
  const float N = (float)NN_;
  float mus[3] = {st[0]/N, st[1]/N, st[2]/N};
  float var_src = st[3] - N*(mus[0]*mus[0] + mus[1]*mus[1] + mus[2]*mus[2]);
  float mut[3] = {sums[0]/N, sums[1]/N, sums[2]/N};
  float H[3][3];
  for (int d = 0; d < 3; ++d)
    for (int e = 0; e < 3; ++e)
      H[d][e] = sums[3 + 3*d + e] - N*mus[d]*mut[e];

  float A[3][3];
  for (int i = 0; i < 3; ++i)
    for (int j = 0; j < 3; ++j)
      A[i][j] = H[0][i]*H[0][j] + H[1][i]*H[1][j] + H[2][i]*H[2][j];
  float V[3][3] = {{1,0,0},{0,1,0},{0,0,1}};
  const int PP[3] = {0,0,1}, QQ[3] = {1,2,2};
  for (int sweep = 0; sweep < 7; ++sweep) {
    for (int r = 0; r < 3; ++r) {
      int p = PP[r], q = QQ[r];
      float apq = A[p][q];
      if (fabsf(apq) < 1e-30f) continue;
      float tau = (A[q][q] - A[p][p]) / (2.f*apq);
      float tt = (tau >= 0.f ? 1.f : -1.f) / (fabsf(tau) + sqrtf(1.f + tau*tau));
      float c = rsqrtf(1.f + tt*tt), s = tt*c;
      for (int k = 0; k < 3; ++k) { float akp=A[k][p], akq=A[k][q];
        A[k][p]=c*akp - s*akq; A[k][q]=s*akp + c*akq; }
      for (int k = 0; k < 3; ++k) { float apk=A[p][k], aqk=A[q][k];
        A[p][k]=c*apk - s*aqk; A[q][k]=s*apk + c*aqk; }
      for (int k = 0; k < 3; ++k) { float vkp=V[k][p], vkq=V[k][q];
        V[k][p]=c*vkp - s*vkq; V[k][q]=s*vkp + c*vkq; }
    }
  }
  float lam[3] = {A[0][0], A[1][1], A[2][2]};
  int o[3] = {0,1,2};
  if (lam[o[1]] > lam[o[0]]) { int t_=o[0]; o[0]=o[1]; o[1]=t_; }
  if (lam[o[2]] > lam[o[0]]) { int t_=o[0]; o[0]=o[2]; o[2]=t_; }
  if (lam[o[2]] > lam[o[1]]) { int t_=o[1]; o[1]=o[2]; o[2]=t_; }
  float v0[3] = {V[0][o[0]], V[1][o[0]], V[2][o[0]]};
  float v1[3] = {V[0][o[1]], V[1][o[1]], V[2][o[1]]};
  float v2[3] = {V[0][o[2]], V[1][o[2]], V[2][o[2]]};

  float hv0[3], hv1[3], hv2[3];
  for (int d = 0; d < 3; ++d) {
    hv0[d] = H[d][0]*v0[0] + H[d][1]*v0[1] + H[d][2]*v0[2];
    hv1[d] = H[d][0]*v1[0] + H[d][1]*v1[1] + H[d][2]*v1[2];
    hv2[d] = H[d][0]*v2[0] + H[d][1]*v2[1] + H[d][2]*v2[2];
  }
  float S0 = sqrtf(hv0[0]*hv0[0] + hv0[1]*hv0[1] + hv0[2]*hv0[2]);
  float u0[3];
  float inv0 = (S0 > 1e-20f) ? 1.f/S0 : 0.f;
  u0[0]=hv0[0]*inv0; u0[1]=hv0[1]*inv0; u0[2]=hv0[2]*inv0;
  if (S0 <= 1e-20f) { u0[0]=1.f; u0[1]=0.f; u0[2]=0.f; }
  float S1 = sqrtf(hv1[0]*hv1[0] + hv1[1]*hv1[1] + hv1[2]*hv1[2]);
  float d01 = u0[0]*hv1[0] + u0[1]*hv1[1] + u0[2]*hv1[2];
  float w1[3] = {hv1[0]-d01*u0[0], hv1[1]-d01*u0[1], hv1[2]-d01*u0[2]};
  float n1 = sqrtf(w1[0]*w1[0] + w1[1]*w1[1] + w1[2]*w1[2]);
  float u1[3];
  if (n1 > 1e-20f) { u1[0]=w1[0]/n1; u1[1]=w1[1]/n1; u1[2]=w1[2]/n1; }
  else {
    float ax = fabsf(u0[0]);
    float t0[3] = { ax < 0.9f ? 1.f : 0.f, ax < 0.9f ? 0.f : 1.f, 0.f };
    u1[0] = u0[1]*t0[2]-u0[2]*t0[1];
    u1[1] = u0[2]*t0[0]-u0[0]*t0[2];
    u1[2] = u0[0]*t0[1]-u0[1]*t0[0];
    float nn = sqrtf(u1[0]*u1[0]+u1[1]*u1[1]+u1[2]*u1[2]);
    u1[0]/=nn; u1[1]/=nn; u1[2]/=nn;
  }
  float u2[3] = {u0[1]*u1[2]-u0[2]*u1[1],
                 u0[2]*u1[0]-u0[0]*u1[2],
                 u0[0]*u1[1]-u0[1]*u1[0]};
  float s2p = u2[0]*hv2[0] + u2[1]*hv2[1] + u2[2]*hv2[2];
  float dV = v0[0]*(v1[1]*v2[2]-v1[2]*v2[1])
           - v0[1]*(v1[0]*v2[2]-v1[2]*v2[0])
           + v0[2]*(v1[0]*v2[1]-v1[1]*v2[0]);
  dV = (dV >= 0.f) ? 1.f : -1.f;
  float traceS = S0 + S1 + dV * s2p;

  float R[3][3];
  for (int i = 0; i < 3; ++i)
    for (int k = 0; k < 3; ++k)
      R[i][k] = v0[i]*u0[k] + v1[i]*u1[k] + dV*v2[i]*u2[k];

  float scale = traceS / (var_src + 1e-8f);
  scale = fminf(fmaxf(scale, 0.5f), 2.0f);
  float tv[3];
  for (int e = 0; e < 3; ++e)
    tv[e] = mut[e] - scale*(R[e][0]*mus[0] + R[e][1]*mus[1] + R[e][2]*mus[2]);

  float* T = ws + OFF_T + b*16;
  for (int e = 0; e < 3; ++e)
    for (int d = 0; d < 3; ++d)
      T[3*e + d] = R[e][d];
  T[9]  = tv[0]; T[10] = tv[1]; T[11] = tv[2];
  T[12] = scale;
}

// ------------------------------------------- fused final both directions --
__global__ __launch_bounds__(BLOCK, 8) void icp_final(const float* __restrict__ src,
                                                      const float* __restrict__ tgt,
                                                      float* __restrict__ out,
                                                      float* __restrict__ ws) {
  __shared__ __align__(16) float tx_[TCHF], ty_[TCHF], tz_[TCHF], tw_[TCHF];
  int b = blockIdx.z, yk = blockIdx.y, tid = threadIdx.x;
  int dir = yk >> 4, kc = yk & 15;
  const float* T = ws + OFF_T + b*16;
  float sc = T[12];
  int n0 = blockIdx.x * (BLOCK * P) + tid;
  f32x2 nxp[P], nyp[P], nzp[P];
  float pp[P];

  if (dir == 0) {
#pragma unroll
    for (int k = 0; k < P; ++k) {
      const float* sp = src + ((size_t)b * NN_ + n0 + k*BLOCK) * 3;
      float sx = sp[0], sy = sp[1], sz = sp[2];
      float px = fmaf(sc, fmaf(T[0], sx, fmaf(T[1], sy, T[2]*sz)), T[9]);
      float py = fmaf(sc, fmaf(T[3], sx, fmaf(T[4], sy, T[5]*sz)), T[10]);
      float pz = fmaf(sc, fmaf(T[6], sx, fmaf(T[7], sy, T[8]*sz)), T[11]);
      if (kc == 0) {
        float* op = out + 1 + ((size_t)b * NN_ + n0 + k*BLOCK) * 3;
        op[0] = px; op[1] = py; op[2] = pz;
      }
      pp[k] = fmaf(px, px, fmaf(py, py, pz*pz));
      nxp[k].x = nxp[k].y = -2.f*px;
      nyp[k].x = nyp[k].y = -2.f*py;
      nzp[k].x = nzp[k].y = -2.f*pz;
    }
    const float* tb = tgt + ((size_t)b * MM_ + kc * TCHF) * 3;
    {
      int j = tid;  // TCHF == BLOCK
      float tx = tb[3*j], ty = tb[3*j+1], tz = tb[3*j+2];
      tx_[j] = tx; ty_[j] = ty; tz_[j] = tz;
      tw_[j] = fmaf(tx, tx, fmaf(ty, ty, tz*tz));
    }
  } else {
#pragma unroll
    for (int k = 0; k < P; ++k) {
      const float* qp = tgt + ((size_t)b * MM_ + n0 + k*BLOCK) * 3;
      float qx = qp[0], qy = qp[1], qz = qp[2];
      pp[k] = fmaf(qx, qx, fmaf(qy, qy, qz*qz));
      nxp[k].x = nxp[k].y = -2.f*qx;
      nyp[k].x = nyp[k].y = -2.f*qy;
      nzp[k].x = nzp[k].y = -2.f*qz;
    }
    const float* sb = src + ((size_t)b * NN_ + kc * TCHF) * 3;
    {
      int j = tid;
      float sx = sb[3*j], sy = sb[3*j+1], sz = sb[3*j+2];
      float ax = fmaf(sc, fmaf(T[0], sx, fmaf(T[1], sy, T[2]*sz)), T[9]);
      float ay = fmaf(sc, fmaf(T[3], sx, fmaf(T[4], sy, T[5]*sz)), T[10]);
      float az = fmaf(sc, fmaf(T[6], sx, fmaf(T[7], sy, T[8]*sz)), T[11]);
      tx_[j] = ax; ty_[j] = ay; tz_[j] = az;
      tw_[j] = fmaf(ax, ax, fmaf(ay, ay, az*az));
    }
  }
  __syncthreads();

  float best[P];
#pragma unroll
  for (int k = 0; k < P; ++k) best[k] = INFINITY;
#pragma unroll 2
  for (int j = 0; j < TCHF; j += 4) {
    f32x4 X = *(const f32x4*)&tx_[j];
    f32x4 Y = *(const f32x4*)&ty_[j];
    f32x4 Z = *(const f32x4*)&tz_[j];
    f32x4 W = *(const f32x4*)&tw_[j];
    f32x2 X0 = {X.x, X.y}, X1 = {X.z, X.w};
    f32x2 Y0 = {Y.x, Y.y}, Y1 = {Y.z, Y.w};
    f32x2 Z0 = {Z.x, Z.y}, Z1 = {Z.z, Z.w};
    f32x2 W0 = {W.x, W.y}, W1 = {W.z, W.w};
#pragma unroll
    for (int k = 0; k < P; ++k) {
      f32x2 v0 = pk_fma(nxp[k], X0, pk_fma(nyp[k], Y0, pk_fma(nzp[k], Z0, W0)));
      f32x2 v1 = pk_fma(nxp[k], X1, pk_fma(nyp[k], Y1, pk_fma(nzp[k], Z1, W1)));
      best[k] = fminf(fminf(fminf(v0.x, v0.y), fminf(v1.x, v1.y)), best[k]);
    }
  }
  float* dst = ws + (dir ? OFF_FB : OFF_FA);
#pragma unroll
  for (int k = 0; k < P; ++k) {
    float v = fmaxf(best[k] + pp[k], 0.f);
    atomic_min_f(dst + (size_t)b*NN_ + n0 + k*BLOCK, v);
  }
}

// ------------------------------------------- final combine + per-batch ----
__global__ __launch_bounds__(BLOCK) void icp_fcomb(float* __restrict__ ws) {
  __shared__ float red[4*2];
  int b = blockIdx.x, tid = threadIdx.x;
  float sa = 0.f, sb = 0.f;
  for (int g = 0; g < NN_/BLOCK; ++g) {
    int n = g*BLOCK + tid;
    sa += ws[OFF_FA + (size_t)b*NN_ + n];
    sb += ws[OFF_FB + (size_t)b*NN_ + n];
  }
  for (int m = 32; m; m >>= 1) {
    sa += __shfl_xor(sa, m); sb += __shfl_xor(sb, m);
  }
  int wave = tid >> 6;
  if ((tid & 63) == 0) { red[wave*2] = sa; red[wave*2+1] = sb; }
  __syncthreads();
  if (tid == 0) {
    sa = red[0] + red[2] + red[4] + red[6];
    sb = red[1] + red[3] + red[5] + red[7];
    ws[OFF_CH + b] = sa / (float)NN_ + sb / (float)MM_;
  }
}

// ------------------------------------------------------------ finalize ----
__global__ __launch_bounds__(64) void icp_finalize(float* __restrict__ out,
                                                   const float* __restrict__ ws) {
  if (threadIdx.x == 0) {
    float s = 0.f;
    for (int b = 0; b < NB; ++b) s += ws[OFF_CH + b];
    out[0] = s / (float)NB;
  }
}

// -------------------------------------------------------------- launch ----
extern "C" void kernel_launch(void* const* d_in, const int* in_sizes, int n_in,
                              void* d_out, int out_size, void* d_ws, size_t ws_size,
                              hipStream_t stream) {
  const float* src = (const float*)d_in[0];
  const float* tgt = (const float*)d_in[1];
  float* out = (float*)d_out;
  float* ws  = (float*)d_ws;

  icp_init<<<NB, BLOCK, 0, stream>>>(src, ws);
  for (int it = 0; it < NITER; ++it) {
    icp_nn1<<<dim3(SCH, KCH, NB), BLOCK, 0, stream>>>(src, tgt, ws);
    icp_nn2<<<dim3(SCH2, NB), BLOCK, 0, stream>>>(src, tgt, ws);
    icp_umeyama<<<NB, 64, 0, stream>>>(ws);
  }
  icp_final<<<dim3(SCH, 2*KCHF, NB), BLOCK, 0, stream>>>(src, tgt, out, ws);
  icp_fcomb<<<NB, BLOCK, 0, stream>>>(ws);
  icp_finalize<<<1, 64, 0, stream>>>(out, ws);
}

// Round 14
// 298.427 us; speedup vs baseline: 1.1615x; 1.1615x over previous
//
#include <hip/hip_runtime.h>
#include <math.h>

#define BLOCK 256
#define NB    16
#define NN_   4096
#define MM_   4096
#define NITER 5
#define P     4
#define SCH   4
#define KCH   32
#define TCH   128
#define KCHF  16
#define TCHF  256
#define SCH2  4
#define P2    4

// ws layout (float offsets)
#define OFF_STATS 0
#define OFF_T     64
#define OFF_CH    320
#define OFF_PART  336
#define OFF_ND    2048
#define OFF_FA    67584
#define OFF_FB    133120
#define CLR_BASE  2048
#define CLR_CNT   196608

typedef __attribute__((ext_vector_type(2))) float f32x2;

// Compiler-visible packed FMA: clang selects v_pk_fma_f32 and can
// schedule/CSE/regalloc around it (unlike the previous inline asm).
__device__ __forceinline__ f32x2 pk_fma(f32x2 a, f32x2 b, f32x2 c) {
#if defined(__has_builtin) && __has_builtin(__builtin_elementwise_fma)
  return __builtin_elementwise_fma(a, b, c);
#else
  return a * b + c;  // contracted to v_pk_fma_f32 under -ffp-contract=fast
#endif
}

__device__ __forceinline__ void atomic_min_f(float* p, float v) {
  atomicMin((unsigned int*)p, __float_as_uint(v));  // valid for v >= 0
}

// ------------------------------------------------- init + clear minbufs ---
__global__ __launch_bounds__(BLOCK) void icp_init(const float* __restrict__ src,
                                                  float* __restrict__ ws) {
  int b = blockIdx.x, tid = threadIdx.x;
  for (int i = b*BLOCK + tid; i < CLR_CNT; i += NB*BLOCK)
    ws[CLR_BASE + i] = INFINITY;
  const float* sb = src + (size_t)b * NN_ * 3;
  float sx = 0.f, sy = 0.f, sz = 0.f, ss = 0.f;
  for (int n = tid; n < NN_; n += BLOCK) {
    float x = sb[3*n], y = sb[3*n+1], z = sb[3*n+2];
    sx += x; sy += y; sz += z;
    ss += fmaf(x, x, fmaf(y, y, z*z));
  }
  __shared__ float red[16];
  for (int m = 32; m; m >>= 1) {
    sx += __shfl_xor(sx, m); sy += __shfl_xor(sy, m);
    sz += __shfl_xor(sz, m); ss += __shfl_xor(ss, m);
  }
  int wave = tid >> 6;
  if ((tid & 63) == 0) {
    red[wave*4+0] = sx; red[wave*4+1] = sy; red[wave*4+2] = sz; red[wave*4+3] = ss;
  }
  __syncthreads();
  if (tid == 0) {
    for (int w = 1; w < 4; ++w) {
      sx += red[w*4+0]; sy += red[w*4+1]; sz += red[w*4+2]; ss += red[w*4+3];
    }
    float* st = ws + OFF_STATS + b*4;
    st[0] = sx; st[1] = sy; st[2] = sz; st[3] = ss;
    float* T = ws + OFF_T + b*16;
    T[0]=1.f; T[1]=0.f; T[2]=0.f;
    T[3]=0.f; T[4]=1.f; T[5]=0.f;
    T[6]=0.f; T[7]=0.f; T[8]=1.f;
    T[9]=0.f; T[10]=0.f; T[11]=0.f; T[12]=1.f;
  }
}

// ---------------------------------------------------------- NN pass 1 -----
__global__ __launch_bounds__(BLOCK, 8) void icp_nn1(const float* __restrict__ src,
                                                    const float* __restrict__ tgt,
                                                    float* __restrict__ ws) {
  __shared__ __align__(16) float tx_[TCH], ty_[TCH], tz_[TCH], tw_[TCH];
  int b = blockIdx.z, kc = blockIdx.y, tid = threadIdx.x;
  int n0 = blockIdx.x * (BLOCK * P) + tid;
  const float* T = ws + OFF_T + b*16;
  float sc = T[12];
  f32x2 nxp[P], nyp[P], nzp[P], p2p[P];
#pragma unroll
  for (int k = 0; k < P; ++k) {
    const float* sp = src + ((size_t)b * NN_ + n0 + k*BLOCK) * 3;
    float sx = sp[0], sy = sp[1], sz = sp[2];
    float px = fmaf(sc, fmaf(T[0], sx, fmaf(T[1], sy, T[2]*sz)), T[9]);
    float py = fmaf(sc, fmaf(T[3], sx, fmaf(T[4], sy, T[5]*sz)), T[10]);
    float pz = fmaf(sc, fmaf(T[6], sx, fmaf(T[7], sy, T[8]*sz)), T[11]);
    nxp[k].x = nxp[k].y = -2.f*px;
    nyp[k].x = nyp[k].y = -2.f*py;
    nzp[k].x = nzp[k].y = -2.f*pz;
    float p2 = fmaf(px, px, fmaf(py, py, pz*pz));
    p2p[k].x = p2p[k].y = p2;
  }
  if (tid < TCH) {
    int j = tid;
    const float* tp = tgt + ((size_t)b * MM_ + kc * TCH + j) * 3;
    float tx = tp[0], ty = tp[1], tz = tp[2];
    tx_[j] = tx; ty_[j] = ty; tz_[j] = tz;
    tw_[j] = fmaf(tx, tx, fmaf(ty, ty, tz*tz));
  }
  __syncthreads();

  int jbase = kc * TCH;
  float best[P];
#pragma unroll
  for (int k = 0; k < P; ++k) best[k] = INFINITY;
#pragma unroll 4
  for (int j = 0; j < TCH; j += 2) {
    f32x2 TX = *(const f32x2*)&tx_[j];
    f32x2 TY = *(const f32x2*)&ty_[j];
    f32x2 TZ = *(const f32x2*)&tz_[j];
    f32x2 TW = *(const f32x2*)&tw_[j];
    unsigned i0 = (unsigned)(jbase + j), i1 = i0 + 1;
#pragma unroll
    for (int k = 0; k < P; ++k) {
      f32x2 v = pk_fma(nxp[k], TX, pk_fma(nyp[k], TY, pk_fma(nzp[k], TZ, TW + p2p[k])));
      float p0 = __uint_as_float((__float_as_uint(v.x) & 0xFFFFF000u) | i0);
      float p1 = __uint_as_float((__float_as_uint(v.y) & 0xFFFFF000u) | i1);
      best[k] = fminf(fminf(p0, p1), best[k]);
    }
  }
#pragma unroll
  for (int k = 0; k < P; ++k)
    atomic_min_f(ws + OFF_ND + (size_t)b*NN_ + n0 + k*BLOCK, best[k]);
}

// ----------------------------------------- NN pass 2: gather + 12-sums ----
__global__ __launch_bounds__(BLOCK) void icp_nn2(const float* __restrict__ src,
                                                 const float* __restrict__ tgt,
                                                 float* __restrict__ ws) {
  __shared__ float red[4*12];
  int b = blockIdx.y, c4 = blockIdx.x, tid = threadIdx.x;
  float acc[12];
#pragma unroll
  for (int c = 0; c < 12; ++c) acc[c] = 0.f;
  for (int k = 0; k < P2; ++k) {
    int n = c4 * (BLOCK*P2) + tid + k*BLOCK;
    size_t slot = OFF_ND + (size_t)b*NN_ + n;
    float bd = ws[slot];
    ws[slot] = INFINITY;  // reset for next iteration
    int bi = (int)(__float_as_uint(bd) & 4095u);
    const float* tp = tgt + ((size_t)b * MM_ + bi) * 3;
    const float* sp = src + ((size_t)b * NN_ + n) * 3;
    float tx = tp[0], ty = tp[1], tz = tp[2];
    float sx = sp[0], sy = sp[1], sz = sp[2];
    acc[0] += tx; acc[1] += ty; acc[2] += tz;
    acc[3] += sx*tx; acc[4] += sx*ty; acc[5] += sx*tz;
    acc[6] += sy*tx; acc[7] += sy*ty; acc[8] += sy*tz;
    acc[9] += sz*tx; acc[10] += sz*ty; acc[11] += sz*tz;
  }
#pragma unroll
  for (int c = 0; c < 12; ++c)
    for (int m = 32; m; m >>= 1) acc[c] += __shfl_xor(acc[c], m);
  int wave = tid >> 6;
  if ((tid & 63) == 0) {
#pragma unroll
    for (int c = 0; c < 12; ++c) red[wave*12 + c] = acc[c];
  }
  __syncthreads();
  if (tid < 12) {
    float s = red[tid] + red[12+tid] + red[24+tid] + red[36+tid];
    ws[OFF_PART + (b*SCH2 + c4)*12 + tid] = s;
  }
}

// --------------------------------------------------- Umeyama (fp32) -------
__global__ __launch_bounds__(64) void icp_umeyama(float* __restrict__ ws) {
  int b = blockIdx.x, tid = threadIdx.x;
  __shared__ float sums[12];
  if (tid < 12) {
    double s = 0.0;
    for (int j = 0; j < SCH2; ++j)
      s += (double)ws[OFF_PART + (b*SCH2 + j)*12 + tid];
    sums[tid] = (float)s;
  }
  __syncthreads();
  if (tid != 0) return;

  const float* st = ws + OFF_STATS + b*4;
  const float N = (float)NN_;
  float mus[3] = {st[0]/N, st[1]/N, st[2]/N};
  float var_src = st[3] - N*(mus[0]*mus[0] + mus[1]*mus[1] + mus[2]*mus[2]);
  float mut[3] = {sums[0]/N, sums[1]/N, sums[2]/N};
  float H[3][3];
  for (int d = 0; d < 3; ++d)
    for (int e = 0; e < 3; ++e)
      H[d][e] = sums[3 + 3*d + e] - N*mus[d]*mut[e];

  float A[3][3];
  for (int i = 0; i < 3; ++i)
    for (int j = 0; j < 3; ++j)
      A[i][j] = H[0][i]*H[0][j] + H[1][i]*H[1][j] + H[2][i]*H[2][j];
  float V[3][3] = {{1,0,0},{0,1,0},{0,0,1}};
  const int PP[3] = {0,0,1}, QQ[3] = {1,2,2};
  for (int sweep = 0; sweep < 7; ++sweep) {
    for (int r = 0; r < 3; ++r) {
      int p = PP[r], q = QQ[r];
      float apq = A[p][q];
      if (fabsf(apq) < 1e-30f) continue;
      float tau = (A[q][q] - A[p][p]) / (2.f*apq);
      float tt = (tau >= 0.f ? 1.f : -1.f) / (fabsf(tau) + sqrtf(1.f + tau*tau));
      float c = rsqrtf(1.f + tt*tt), s = tt*c;
      for (int k = 0; k < 3; ++k) { float akp=A[k][p], akq=A[k][q];
        A[k][p]=c*akp - s*akq; A[k][q]=s*akp + c*akq; }
      for (int k = 0; k < 3; ++k) { float apk=A[p][k], aqk=A[q][k];
        A[p][k]=c*apk - s*aqk; A[q][k]=s*apk + c*aqk; }
      for (int k = 0; k < 3; ++k) { float vkp=V[k][p], vkq=V[k][q];
        V[k][p]=c*vkp - s*vkq; V[k][q]=s*vkp + c*vkq; }
    }
  }
  float lam[3] = {A[0][0], A[1][1], A[2][2]};
  int o[3] = {0,1,2};
  if (lam[o[1]] > lam[o[0]]) { int t_=o[0]; o[0]=o[1]; o[1]=t_; }
  if (lam[o[2]] > lam[o[0]]) { int t_=o[0]; o[0]=o[2]; o[2]=t_; }
  if (lam[o[2]] > lam[o[1]]) { int t_=o[1]; o[1]=o[2]; o[2]=t_; }
  float v0[3] = {V[0][o[0]], V[1][o[0]], V[2][o[0]]};
  float v1[3] = {V[0][o[1]], V[1][o[1]], V[2][o[1]]};
  float v2[3] = {V[0][o[2]], V[1][o[2]], V[2][o[2]]};

  float hv0[3], hv1[3], hv2[3];
  for (int d = 0; d < 3; ++d) {
    hv0[d] = H[d][0]*v0[0] + H[d][1]*v0[1] + H[d][2]*v0[2];
    hv1[d] = H[d][0]*v1[0] + H[d][1]*v1[1] + H[d][2]*v1[2];
    hv2[d] = H[d][0]*v2[0] + H[d][1]*v2[1] + H[d][2]*v2[2];
  }
  float S0 = sqrtf(hv0[0]*hv0[0] + hv0[1]*hv0[1] + hv0[2]*hv0[2]);
  float u0[3];
  float inv0 = (S0 > 1e-20f) ? 1.f/S0 : 0.f;
  u0[0]=hv0[0]*inv0; u0[1]=hv0[1]*inv0; u0[2]=hv0[2]*inv0;
  if (S0 <= 1e-20f) { u0[0]=1.f; u0[1]=0.f; u0[2]=0.f; }
  float S1 = sqrtf(hv1[0]*hv1[0] + hv1[1]*hv1[1] + hv1[2]*hv1[2]);
  float d01 = u0[0]*hv1[0] + u0[1]*hv1[1] + u0[2]*hv1[2];
  float w1[3] = {hv1[0]-d01*u0[0], hv1[1]-d01*u0[1], hv1[2]-d01*u0[2]};
  float n1 = sqrtf(w1[0]*w1[0] + w1[1]*w1[1] + w1[2]*w1[2]);
  float u1[3];
  if (n1 > 1e-20f) { u1[0]=w1[0]/n1; u1[1]=w1[1]/n1; u1[2]=w1[2]/n1; }
  else {
    float ax = fabsf(u0[0]);
    float t0[3] = { ax < 0.9f ? 1.f : 0.f, ax < 0.9f ? 0.f : 1.f, 0.f };
    u1[0] = u0[1]*t0[2]-u0[2]*t0[1];
    u1[1] = u0[2]*t0[0]-u0[0]*t0[2];
    u1[2] = u0[0]*t0[1]-u0[1]*t0[0];
    float nn = sqrtf(u1[0]*u1[0]+u1[1]*u1[1]+u1[2]*u1[2]);
    u1[0]/=nn; u1[1]/=nn; u1[2]/=nn;
  }
  float u2[3] = {u0[1]*u1[2]-u0[2]*u1[1],
                 u0[2]*u1[0]-u0[0]*u1[2],
                 u0[0]*u1[1]-u0[1]*u1[0]};
  float s2p = u2[0]*hv2[0] + u2[1]*hv2[1] + u2[2]*hv2[2];
  float dV = v0[0]*(v1[1]*v2[2]-v1[2]*v2[1])
           - v0[1]*(v1[0]*v2[2]-v1[2]*v2[0])
           + v0[2]*(v1[0]*v2[1]-v1[1]*v2[0]);
  dV = (dV >= 0.f) ? 1.f : -1.f;
  float traceS = S0 + S1 + dV * s2p;

  float R[3][3];
  for (int i = 0; i < 3; ++i)
    for (int k = 0; k < 3; ++k)
      R[i][k] = v0[i]*u0[k] + v1[i]*u1[k] + dV*v2[i]*u2[k];

  float scale = traceS / (var_src + 1e-8f);
  scale = fminf(fmaxf(scale, 0.5f), 2.0f);
  float tv[3];
  for (int e = 0; e < 3; ++e)
    tv[e] = mut[e] - scale*(R[e][0]*mus[0] + R[e][1]*mus[1] + R[e][2]*mus[2]);

  float* T = ws + OFF_T + b*16;
  for (int e = 0; e < 3; ++e)
    for (int d = 0; d < 3; ++d)
      T[3*e + d] = R[e][d];
  T[9]  = tv[0]; T[10] = tv[1]; T[11] = tv[2];
  T[12] = scale;
}

// ------------------------------------------- fused final both directions --
__global__ __launch_bounds__(BLOCK, 8) void icp_final(const float* __restrict__ src,
                                                      const float* __restrict__ tgt,
                                                      float* __restrict__ out,
                                                      float* __restrict__ ws) {
  __shared__ __align__(16) float tx_[TCHF], ty_[TCHF], tz_[TCHF], tw_[TCHF];
  int b = blockIdx.z, yk = blockIdx.y, tid = threadIdx.x;
  int dir = yk >> 4, kc = yk & 15;
  const float* T = ws + OFF_T + b*16;
  float sc = T[12];
  int n0 = blockIdx.x * (BLOCK * P) + tid;
  f32x2 nxp[P], nyp[P], nzp[P];
  float pp[P];

  if (dir == 0) {
#pragma unroll
    for (int k = 0; k < P; ++k) {
      const float* sp = src + ((size_t)b * NN_ + n0 + k*BLOCK) * 3;
      float sx = sp[0], sy = sp[1], sz = sp[2];
      float px = fmaf(sc, fmaf(T[0], sx, fmaf(T[1], sy, T[2]*sz)), T[9]);
      float py = fmaf(sc, fmaf(T[3], sx, fmaf(T[4], sy, T[5]*sz)), T[10]);
      float pz = fmaf(sc, fmaf(T[6], sx, fmaf(T[7], sy, T[8]*sz)), T[11]);
      if (kc == 0) {
        float* op = out + 1 + ((size_t)b * NN_ + n0 + k*BLOCK) * 3;
        op[0] = px; op[1] = py; op[2] = pz;
      }
      pp[k] = fmaf(px, px, fmaf(py, py, pz*pz));
      nxp[k].x = nxp[k].y = -2.f*px;
      nyp[k].x = nyp[k].y = -2.f*py;
      nzp[k].x = nzp[k].y = -2.f*pz;
    }
    const float* tb = tgt + ((size_t)b * MM_ + kc * TCHF) * 3;
    {
      int j = tid;  // TCHF == BLOCK
      float tx = tb[3*j], ty = tb[3*j+1], tz = tb[3*j+2];
      tx_[j] = tx; ty_[j] = ty; tz_[j] = tz;
      tw_[j] = fmaf(tx, tx, fmaf(ty, ty, tz*tz));
    }
  } else {
#pragma unroll
    for (int k = 0; k < P; ++k) {
      const float* qp = tgt + ((size_t)b * MM_ + n0 + k*BLOCK) * 3;
      float qx = qp[0], qy = qp[1], qz = qp[2];
      pp[k] = fmaf(qx, qx, fmaf(qy, qy, qz*qz));
      nxp[k].x = nxp[k].y = -2.f*qx;
      nyp[k].x = nyp[k].y = -2.f*qy;
      nzp[k].x = nzp[k].y = -2.f*qz;
    }
    const float* sb = src + ((size_t)b * NN_ + kc * TCHF) * 3;
    {
      int j = tid;
      float sx = sb[3*j], sy = sb[3*j+1], sz = sb[3*j+2];
      float ax = fmaf(sc, fmaf(T[0], sx, fmaf(T[1], sy, T[2]*sz)), T[9]);
      float ay = fmaf(sc, fmaf(T[3], sx, fmaf(T[4], sy, T[5]*sz)), T[10]);
      float az = fmaf(sc, fmaf(T[6], sx, fmaf(T[7], sy, T[8]*sz)), T[11]);
      tx_[j] = ax; ty_[j] = ay; tz_[j] = az;
      tw_[j] = fmaf(ax, ax, fmaf(ay, ay, az*az));
    }
  }
  __syncthreads();

  float best[P];
#pragma unroll
  for (int k = 0; k < P; ++k) best[k] = INFINITY;
#pragma unroll 4
  for (int j = 0; j < TCHF; j += 2) {
    f32x2 TX = *(const f32x2*)&tx_[j];
    f32x2 TY = *(const f32x2*)&ty_[j];
    f32x2 TZ = *(const f32x2*)&tz_[j];
    f32x2 TW = *(const f32x2*)&tw_[j];
#pragma unroll
    for (int k = 0; k < P; ++k) {
      f32x2 v = pk_fma(nxp[k], TX, pk_fma(nyp[k], TY, pk_fma(nzp[k], TZ, TW)));
      best[k] = fminf(fminf(v.x, v.y), best[k]);
    }
  }
  float* dst = ws + (dir ? OFF_FB : OFF_FA);
#pragma unroll
  for (int k = 0; k < P; ++k) {
    float v = fmaxf(best[k] + pp[k], 0.f);
    atomic_min_f(dst + (size_t)b*NN_ + n0 + k*BLOCK, v);
  }
}

// ------------------------------------------- final combine + per-batch ----
__global__ __launch_bounds__(BLOCK) void icp_fcomb(float* __restrict__ ws) {
  __shared__ float red[4*2];
  int b = blockIdx.x, tid = threadIdx.x;
  float sa = 0.f, sb = 0.f;
  for (int g = 0; g < NN_/BLOCK; ++g) {
    int n = g*BLOCK + tid;
    sa += ws[OFF_FA + (size_t)b*NN_ + n];
    sb += ws[OFF_FB + (size_t)b*NN_ + n];
  }
  for (int m = 32; m; m >>= 1) {
    sa += __shfl_xor(sa, m); sb += __shfl_xor(sb, m);
  }
  int wave = tid >> 6;
  if ((tid & 63) == 0) { red[wave*2] = sa; red[wave*2+1] = sb; }
  __syncthreads();
  if (tid == 0) {
    sa = red[0] + red[2] + red[4] + red[6];
    sb = red[1] + red[3] + red[5] + red[7];
    ws[OFF_CH + b] = sa / (float)NN_ + sb / (float)MM_;
  }
}

// ------------------------------------------------------------ finalize ----
__global__ __launch_bounds__(64) void icp_finalize(float* __restrict__ out,
                                                   const float* __restrict__ ws) {
  if (threadIdx.x == 0) {
    float s = 0.f;
    for (int b = 0; b < NB; ++b) s += ws[OFF_CH + b];
    out[0] = s / (float)NB;
  }
}

// -------------------------------------------------------------- launch ----
extern "C" void kernel_launch(void* const* d_in, const int* in_sizes, int n_in,
                              void* d_out, int out_size, void* d_ws, size_t ws_size,
                              hipStream_t stream) {
  const float* src = (const float*)d_in[0];
  const float* tgt = (const float*)d_in[1];
  float* out = (float*)d_out;
  float* ws  = (float*)d_ws;

  icp_init<<<NB, BLOCK, 0, stream>>>(src, ws);
  for (int it = 0; it < NITER; ++it) {
    icp_nn1<<<dim3(SCH, KCH, NB), BLOCK, 0, stream>>>(src, tgt, ws);
    icp_nn2<<<dim3(SCH2, NB), BLOCK, 0, stream>>>(src, tgt, ws);
    icp_umeyama<<<NB, 64, 0, stream>>>(ws);
  }
  icp_final<<<dim3(SCH, 2*KCHF, NB), BLOCK, 0, stream>>>(src, tgt, out, ws);
  icp_fcomb<<<NB, BLOCK, 0, stream>>>(ws);
  icp_finalize<<<1, 64, 0, stream>>>(out, ws);
}